// Round 18
// baseline (820.864 us; speedup 1.0000x reference)
//
#include <hip/hip_runtime.h>
#include <hip/hip_bf16.h>
#include <math.h>

#define NN 512   // hidden states
#define MM 256   // timesteps / emission symbols
#define BB 128   // batch

typedef float        f32x4 __attribute__((ext_vector_type(4)));
typedef unsigned int u32;
typedef u32          u32x2 __attribute__((ext_vector_type(2)));
typedef unsigned long long u64;
typedef int          i32x8 __attribute__((ext_vector_type(8)));

#define LOG16F 2.772588722239781f
#define SCL1   0x7F   // E8M0 scale byte = 1.0

__device__ __forceinline__ float wave_max(float v) {
#pragma unroll
    for (int o = 32; o > 0; o >>= 1) v = fmaxf(v, __shfl_xor(v, o));
    return v;
}
__device__ __forceinline__ float wave_sum(float v) {
#pragma unroll
    for (int o = 32; o > 0; o >>= 1) v += __shfl_xor(v, o);
    return v;
}

// ---------------- preprocessing (3 kernels, unchanged from r14) ----------------

__global__ void k_col_lse(const float* __restrict__ T, float* __restrict__ c) {
    int k = blockIdx.x, j = threadIdx.x;
    float m = -INFINITY, s = 0.f;
#pragma unroll
    for (int q = 0; q < 8; ++q) {
        float x = T[(q * 64 + j) * NN + k];
        if (x > m) { s = s * __expf(m - x) + 1.f; m = x; }
        else       { s += __expf(x - m); }
    }
    float mw = wave_max(m);
    float sw = wave_sum(s * __expf(m - mw));
    if (j == 0) c[k] = mw + __logf(sw);
}

__global__ void k_rowM(const float* __restrict__ T, const float* __restrict__ c,
                       float* __restrict__ M) {
    int i = blockIdx.x, j = threadIdx.x;
    float mx = -INFINITY;
#pragma unroll
    for (int d = 0; d < 8; ++d) {
        int k = j * 8 + d;
        mx = fmaxf(mx, T[i * NN + k] - c[k]);
    }
    mx = wave_max(mx);
    if (j == 0) M[i] = mx - __logf(64.f);
}

__global__ void k_prep(const float* __restrict__ T, const float* __restrict__ c,
                       const float* __restrict__ M, const float* __restrict__ pr,
                       const float* __restrict__ E,
                       float* __restrict__ lp2, u32* __restrict__ PA,
                       float* __restrict__ EX) {
    int blk = blockIdx.x, l = threadIdx.x;
    if (blk < 512) {
        float mm = -INFINITY;
#pragma unroll
        for (int q = 0; q < 8; ++q) mm = fmaxf(mm, M[q * 64 + l]);
        float CMv = wave_max(mm);
        int i = blk;
        float v[4];
        float mx = -INFINITY;
#pragma unroll
        for (int d = 0; d < 4; ++d) {
            v[d] = E[i * MM + l * 4 + d];
            mx = fmaxf(mx, v[d]);
        }
        mx = wave_max(mx);
        float s = 0.f;
#pragma unroll
        for (int d = 0; d < 4; ++d) s += __expf(v[d] - mx);
        s = wave_sum(s);
        float lse = mx + __logf(s);
        float add = M[i] - CMv - LOG16F - lse;
#pragma unroll
        for (int d = 0; d < 4; ++d)
            EX[(size_t)(l * 4 + d) * NN + i] = __expf(v[d] + add);
    } else if (blk < 640) {
        int bb = blk - 512;
        int tile = bb >> 2, kc = bb & 3;
        int row = tile * 16 + (l & 15);
        int kb  = kc * 128 + (l >> 4) * 32;
        float Mi = M[row];                // = rowmax - log64
        i32x8 dd;
#pragma unroll
        for (int q = 0; q < 8; ++q) {
            float p0 = __expf(T[row * NN + kb + 4*q + 0] - c[kb + 4*q + 0] - Mi);
            float p1 = __expf(T[row * NN + kb + 4*q + 1] - c[kb + 4*q + 1] - Mi);
            float p2 = __expf(T[row * NN + kb + 4*q + 2] - c[kb + 4*q + 2] - Mi);
            float p3 = __expf(T[row * NN + kb + 4*q + 3] - c[kb + 4*q + 3] - Mi);
            int d = 0;
            d = __builtin_amdgcn_cvt_pk_fp8_f32(p0, p1, d, false);
            d = __builtin_amdgcn_cvt_pk_fp8_f32(p2, p3, d, true);
            dd[q] = d;
        }
        *(i32x8*)(PA + ((size_t)bb * 64 + l) * 8) = dd;
    } else {
        float mm = -INFINITY;
#pragma unroll
        for (int q = 0; q < 8; ++q) mm = fmaxf(mm, M[q * 64 + l]);
        float CMv = wave_max(mm);
        float x[8];
        float mx = -INFINITY;
#pragma unroll
        for (int q = 0; q < 8; ++q) {
            x[q] = pr[q * 64 + l];
            mx = fmaxf(mx, x[q]);
        }
        mx = wave_max(mx);
        float s = 0.f;
#pragma unroll
        for (int q = 0; q < 8; ++q) s += __expf(x[q] - mx);
        s = wave_sum(s);
        float lse = mx + __logf(s);
#pragma unroll
        for (int q = 0; q < 8; ++q) {
            int i = q * 64 + l;
            lp2[i] = __expf(x[q] - lse - M[i] + CMv + LOG16F);
        }
    }
}

// 16 MFMA (4 tiles x 4 kc) on shared A-frags, B from given us8 buffer.
#define MFMA_BLOCK(UB, SACC)                                                     \
    {                                                                            \
        f32x4 _a0={0.f,0.f,0.f,0.f}, _a1={0.f,0.f,0.f,0.f};                      \
        f32x4 _a2={0.f,0.f,0.f,0.f}, _a3={0.f,0.f,0.f,0.f};                      \
        f32x4 _b0={0.f,0.f,0.f,0.f}, _b1={0.f,0.f,0.f,0.f};                      \
        f32x4 _b2={0.f,0.f,0.f,0.f}, _b3={0.f,0.f,0.f,0.f};                      \
        __builtin_amdgcn_s_setprio(1);                                           \
        _Pragma("unroll")                                                        \
        for (int kc = 0; kc < 2; ++kc) {                                         \
            i32x8 bbA = *(const i32x8*)((UB) + kc * 128 + h32);                  \
            i32x8 bbB = *(const i32x8*)((UB) + (kc + 2) * 128 + h32);            \
            _a0 = __builtin_amdgcn_mfma_scale_f32_16x16x128_f8f6f4(pa[0*4+kc],   bbA, _a0, 0,0,0, SCL1, 0, SCL1); \
            _a1 = __builtin_amdgcn_mfma_scale_f32_16x16x128_f8f6f4(pa[1*4+kc],   bbA, _a1, 0,0,0, SCL1, 0, SCL1); \
            _a2 = __builtin_amdgcn_mfma_scale_f32_16x16x128_f8f6f4(pa[2*4+kc],   bbA, _a2, 0,0,0, SCL1, 0, SCL1); \
            _a3 = __builtin_amdgcn_mfma_scale_f32_16x16x128_f8f6f4(pa[3*4+kc],   bbA, _a3, 0,0,0, SCL1, 0, SCL1); \
            _b0 = __builtin_amdgcn_mfma_scale_f32_16x16x128_f8f6f4(pa[0*4+kc+2], bbB, _b0, 0,0,0, SCL1, 0, SCL1); \
            _b1 = __builtin_amdgcn_mfma_scale_f32_16x16x128_f8f6f4(pa[1*4+kc+2], bbB, _b1, 0,0,0, SCL1, 0, SCL1); \
            _b2 = __builtin_amdgcn_mfma_scale_f32_16x16x128_f8f6f4(pa[2*4+kc+2], bbB, _b2, 0,0,0, SCL1, 0, SCL1); \
            _b3 = __builtin_amdgcn_mfma_scale_f32_16x16x128_f8f6f4(pa[3*4+kc+2], bbB, _b3, 0,0,0, SCL1, 0, SCL1); \
        }                                                                        \
        __builtin_amdgcn_s_setprio(0);                                           \
        SACC[0] = _a0 + _b0; SACC[1] = _a1 + _b1;                                \
        SACC[2] = _a2 + _b2; SACC[3] = _a3 + _b3;                                \
    }

// load 4 f32x4 EX slices for row o
#define EX_LOAD(DST, O)                                                          \
    {                                                                            \
        const float* _exr = EX + (size_t)(O) * NN;                               \
        _Pragma("unroll")                                                        \
        for (int ti = 0; ti < 4; ++ti)                                           \
            DST[ti] = *(const f32x4*)(_exr + (w * 4 + ti) * 16 + r4);            \
    }

// S2: e4 = ex*sacc, block-partial into rB (per-wave slot)
#define REDUCE_S2(E4, EXV, SACC, RBUF)                                           \
    {                                                                            \
        float _loc = 0.f;                                                        \
        _Pragma("unroll")                                                        \
        for (int ti = 0; ti < 4; ++ti)                                           \
            _Pragma("unroll")                                                    \
            for (int r = 0; r < 4; ++r) {                                        \
                float _e = EXV[ti][r] * SACC[ti][r];                             \
                E4[ti][r] = _e; _loc += _e;                                      \
            }                                                                    \
        _loc += __shfl_xor(_loc, 16);                                            \
        _loc += __shfl_xor(_loc, 32);                                            \
        if (l == 0) RBUF[w] = _loc;                                              \
    }

// S3: readback S, publish quantized e4, return lS via variable LSN
#define FINISH_S3(E4, RBUF, UBUF, LSN)                                           \
    {                                                                            \
        f32x4 _s0 = *(const f32x4*)(RBUF);                                       \
        f32x4 _s1 = *(const f32x4*)((RBUF) + 4);                                 \
        f32x4 _ss = _s0 + _s1;                                                   \
        float _S = (_ss[0] + _ss[1]) + (_ss[2] + _ss[3]);                        \
        _S = fmaxf(_S, 1e-35f);                                                  \
        float _sc = __builtin_amdgcn_rcpf(_S) * 16.f;                            \
        if ((l & 15) == 0) {                                                     \
            _Pragma("unroll")                                                    \
            for (int ti = 0; ti < 4; ++ti) {                                     \
                int _d = 0;                                                      \
                _d = __builtin_amdgcn_cvt_pk_fp8_f32(E4[ti][0] * _sc, E4[ti][1] * _sc, _d, false); \
                _d = __builtin_amdgcn_cvt_pk_fp8_f32(E4[ti][2] * _sc, E4[ti][3] * _sc, _d, true);  \
                *(u32*)&(UBUF)[ubase[ti]] = (u32)_d;                             \
            }                                                                    \
        }                                                                        \
        LSN = __logf(_S);                                                        \
    }

// ---------------- the scan: 2 batches per block, phase-staggered ----------------
// 64 blocks x 512 threads (8 waves). Batch A = 2*blockIdx, B = 2*blockIdx+1.
// Shared P A-frags (128 AGPR). Each phase: one batch's {ds_read,MFMA,reduce}
// runs concurrently with the OTHER batch's {S-readback, log, quantize, publish}
// -> the independent epilogue fills the MFMA/LDS dependency-chain latency.
// Numerics per batch identical to r14 (fresh 16/S_t, 2 barriers per batch-step).
__global__ __launch_bounds__(512, 2) void k_scan(
        const int* __restrict__ obs, const float* __restrict__ lp2,
        const float* __restrict__ Mrow, const u32* __restrict__ PAu,
        const float* __restrict__ EX, float* __restrict__ out) {
    int blk = blockIdx.x, tid = threadIdx.x;
    int bA = blk * 2, bB = blk * 2 + 1;
    int w = tid >> 6, l = tid & 63;
    int h32 = (l >> 4) * 32;
    int r4 = (l >> 4) * 4;
    __shared__ unsigned char usA[NN] __attribute__((aligned(64)));
    __shared__ unsigned char usB[NN] __attribute__((aligned(64)));
    __shared__ float rA_[8] __attribute__((aligned(16)));
    __shared__ float rB_[8] __attribute__((aligned(16)));
    __shared__ int obs_s[2][MM];
    if (tid < MM) obs_s[0][tid] = obs[(size_t)bA * MM + tid];
    else          obs_s[1][tid - MM] = obs[(size_t)bB * MM + (tid - MM)];

    float mm = -INFINITY;
#pragma unroll
    for (int q = 0; q < 8; ++q) mm = fmaxf(mm, Mrow[q * 64 + l]);
    float C_M = wave_max(mm);

    i32x8 pa[16];
#pragma unroll
    for (int ti = 0; ti < 4; ++ti)
#pragma unroll
        for (int kc = 0; kc < 4; ++kc)
            pa[ti * 4 + kc] = *(const i32x8*)(PAu
                + ((size_t)(((w * 4 + ti) * 4 + kc) * 64) + l) * 8);
#pragma unroll
    for (int q = 0; q < 16; ++q) asm volatile("" : "+a"(pa[q]));

    int ubase[4];
#pragma unroll
    for (int ti = 0; ti < 4; ++ti) ubase[ti] = (w * 4 + ti) * 16 + r4;
    __syncthreads();                      // obs_s ready

    // ---- t=0 for both batches ----
    f32x4 e4A[4], e4B[4], exv[4];
    {
        int oA = obs_s[0][0];
        EX_LOAD(exv, oA);
        f32x4 lpv[4];
#pragma unroll
        for (int ti = 0; ti < 4; ++ti)
            lpv[ti] = *(const f32x4*)(lp2 + (w * 4 + ti) * 16 + r4);
        f32x4 sac0[4];
#pragma unroll
        for (int ti = 0; ti < 4; ++ti) sac0[ti] = lpv[ti];
        REDUCE_S2(e4A, exv, sac0, rA_);
        int oB = obs_s[1][0];
        EX_LOAD(exv, oB);
        REDUCE_S2(e4B, exv, sac0, rB_);
    }
    __syncthreads();                      // rA_, rB_ visible
    float lSA, lSB, KA, KB;
    FINISH_S3(e4A, rA_, usA, lSA);        // publish u_A(0)
    if (tid == 0) out[(size_t)bA * MM + 0] = lSA;
    KA = C_M + lSA;
    // B's S3(0) deferred to the loop's first PHASE0 (needs its own barrier slot)
    // pre-issue ex_A(1)
    f32x4 exA[4], exB[4];
    EX_LOAD(exA, obs_s[0][1]);
    __syncthreads();                      // usA visible; rB_ still intact

    f32x4 sacc[4];

#pragma unroll 1
    for (int t = 1; t < MM; ++t) {
        // ---- PHASE0: MFMA_A(t) + S2_A(t)  ||  S3_B(t-1) ----
        MFMA_BLOCK(usA, sacc);
        if (t == 1) {
            FINISH_S3(e4B, rB_, usB, lSB);    // publish u_B(0)
            if (tid == 0) out[(size_t)bB * MM + 0] = lSB;
            KB = C_M + lSB;
        } else {
            FINISH_S3(e4B, rB_, usB, lSB);    // publish u_B(t-1)
            if (tid == 0) out[(size_t)bB * MM + (t - 1)] = KB + lSB;
            KB += C_M + lSB;
        }
        REDUCE_S2(e4A, exA, sacc, rA_);
        EX_LOAD(exB, obs_s[1][t]);            // in flight across barrier
        __syncthreads();                      // bar: rA_ ready; usB visible

        // ---- PHASE1: MFMA_B(t) + S2_B(t)  ||  S3_A(t) ----
        MFMA_BLOCK(usB, sacc);
        {
            FINISH_S3(e4A, rA_, usA, lSA);    // publish u_A(t)
            if (tid == 0) out[(size_t)bA * MM + t] = KA + lSA;
            KA += C_M + lSA;
        }
        REDUCE_S2(e4B, exB, sacc, rB_);
        EX_LOAD(exA, obs_s[0][(t + 1 < MM) ? t + 1 : t]);  // in flight across bar
        __syncthreads();                      // bar: rB_ ready; usA visible
    }

    // ---- tail: S3_B(255) (no publish needed, just the output) ----
    {
        f32x4 s0 = *(const f32x4*)rB_;
        f32x4 s1 = *(const f32x4*)(rB_ + 4);
        f32x4 ss = s0 + s1;
        float S = (ss[0] + ss[1]) + (ss[2] + ss[3]);
        S = fmaxf(S, 1e-35f);
        float lSn = __logf(S);
        if (tid == 0) out[(size_t)bB * MM + (MM - 1)] = KB + lSn;
    }
}

extern "C" void kernel_launch(void* const* d_in, const int* in_sizes, int n_in,
                              void* d_out, int out_size, void* d_ws, size_t ws_size,
                              hipStream_t stream) {
    const int*   obs = (const int*)d_in[0];
    const float* pri = (const float*)d_in[1];
    const float* T   = (const float*)d_in[2];
    const float* E   = (const float*)d_in[3];
    float* out = (float*)d_out;
    char* ws = (char*)d_ws;

    float* c   = (float*)(ws + 0);
    float* lp2 = (float*)(ws + 2048);
    float* M   = (float*)(ws + 4096);
    u32*   PA  = (u32*)(ws + 8192);                       // 256 KB fp8 A-frags
    float* EX  = (float*)(ws + 8192 + 256 * 1024);        // 512 KB

    k_col_lse<<<512, 64, 0, stream>>>(T, c);
    k_rowM   <<<512, 64, 0, stream>>>(T, c, M);
    k_prep   <<<641, 64, 0, stream>>>(T, c, M, pri, E, lp2, PA, EX);
    k_scan   <<<BB / 2, 512, 0, stream>>>(obs, lp2, M, PA, EX, out);
}

// Round 19
// 321.352 us; speedup vs baseline: 2.5544x; 2.5544x over previous
//
#include <hip/hip_runtime.h>
#include <hip/hip_bf16.h>
#include <math.h>

#define NN 512   // hidden states
#define MM 256   // timesteps / emission symbols
#define BB 128   // batch

typedef float        f32x4 __attribute__((ext_vector_type(4)));
typedef unsigned int u32;
typedef u32          u32x2 __attribute__((ext_vector_type(2)));
typedef unsigned long long u64;
typedef int          i32x8 __attribute__((ext_vector_type(8)));

#define LOG16F 2.772588722239781f
#define SCL1   0x7F   // E8M0 scale byte = 1.0

__device__ __forceinline__ float wave_max(float v) {
#pragma unroll
    for (int o = 32; o > 0; o >>= 1) v = fmaxf(v, __shfl_xor(v, o));
    return v;
}
__device__ __forceinline__ float wave_sum(float v) {
#pragma unroll
    for (int o = 32; o > 0; o >>= 1) v += __shfl_xor(v, o);
    return v;
}

// ---------------- preprocessing (3 kernels, unchanged from r14) ----------------

__global__ void k_col_lse(const float* __restrict__ T, float* __restrict__ c) {
    int k = blockIdx.x, j = threadIdx.x;
    float m = -INFINITY, s = 0.f;
#pragma unroll
    for (int q = 0; q < 8; ++q) {
        float x = T[(q * 64 + j) * NN + k];
        if (x > m) { s = s * __expf(m - x) + 1.f; m = x; }
        else       { s += __expf(x - m); }
    }
    float mw = wave_max(m);
    float sw = wave_sum(s * __expf(m - mw));
    if (j == 0) c[k] = mw + __logf(sw);
}

__global__ void k_rowM(const float* __restrict__ T, const float* __restrict__ c,
                       float* __restrict__ M) {
    int i = blockIdx.x, j = threadIdx.x;
    float mx = -INFINITY;
#pragma unroll
    for (int d = 0; d < 8; ++d) {
        int k = j * 8 + d;
        mx = fmaxf(mx, T[i * NN + k] - c[k]);
    }
    mx = wave_max(mx);
    if (j == 0) M[i] = mx - __logf(64.f);
}

__global__ void k_prep(const float* __restrict__ T, const float* __restrict__ c,
                       const float* __restrict__ M, const float* __restrict__ pr,
                       const float* __restrict__ E,
                       float* __restrict__ lp2, u32* __restrict__ PA,
                       float* __restrict__ EX) {
    int blk = blockIdx.x, l = threadIdx.x;
    if (blk < 512) {
        float mm = -INFINITY;
#pragma unroll
        for (int q = 0; q < 8; ++q) mm = fmaxf(mm, M[q * 64 + l]);
        float CMv = wave_max(mm);
        int i = blk;
        float v[4];
        float mx = -INFINITY;
#pragma unroll
        for (int d = 0; d < 4; ++d) {
            v[d] = E[i * MM + l * 4 + d];
            mx = fmaxf(mx, v[d]);
        }
        mx = wave_max(mx);
        float s = 0.f;
#pragma unroll
        for (int d = 0; d < 4; ++d) s += __expf(v[d] - mx);
        s = wave_sum(s);
        float lse = mx + __logf(s);
        float add = M[i] - CMv - LOG16F - lse;
#pragma unroll
        for (int d = 0; d < 4; ++d)
            EX[(size_t)(l * 4 + d) * NN + i] = __expf(v[d] + add);
    } else if (blk < 640) {
        int bb = blk - 512;
        int tile = bb >> 2, kc = bb & 3;
        int row = tile * 16 + (l & 15);
        int kb  = kc * 128 + (l >> 4) * 32;
        float Mi = M[row];                // = rowmax - log64
        i32x8 dd;
#pragma unroll
        for (int q = 0; q < 8; ++q) {
            float p0 = __expf(T[row * NN + kb + 4*q + 0] - c[kb + 4*q + 0] - Mi);
            float p1 = __expf(T[row * NN + kb + 4*q + 1] - c[kb + 4*q + 1] - Mi);
            float p2 = __expf(T[row * NN + kb + 4*q + 2] - c[kb + 4*q + 2] - Mi);
            float p3 = __expf(T[row * NN + kb + 4*q + 3] - c[kb + 4*q + 3] - Mi);
            int d = 0;
            d = __builtin_amdgcn_cvt_pk_fp8_f32(p0, p1, d, false);
            d = __builtin_amdgcn_cvt_pk_fp8_f32(p2, p3, d, true);
            dd[q] = d;
        }
        *(i32x8*)(PA + ((size_t)bb * 64 + l) * 8) = dd;
    } else {
        float mm = -INFINITY;
#pragma unroll
        for (int q = 0; q < 8; ++q) mm = fmaxf(mm, M[q * 64 + l]);
        float CMv = wave_max(mm);
        float x[8];
        float mx = -INFINITY;
#pragma unroll
        for (int q = 0; q < 8; ++q) {
            x[q] = pr[q * 64 + l];
            mx = fmaxf(mx, x[q]);
        }
        mx = wave_max(mx);
        float s = 0.f;
#pragma unroll
        for (int q = 0; q < 8; ++q) s += __expf(x[q] - mx);
        s = wave_sum(s);
        float lse = mx + __logf(s);
#pragma unroll
        for (int q = 0; q < 8; ++q) {
            int i = q * 64 + l;
            lp2[i] = __expf(x[q] - lse - M[i] + CMv + LOG16F);
        }
    }
}

// ---------------- the scan (MX K=128, 16 waves, VGPR-resident A-frags) -------
// One block per batch, 1024 threads = 16 waves. Wave w owns i-tiles 2w, 2w+1.
// pa = 8 x i32x8 = 64 regs/lane, NO AGPR pin: small enough for the compiler
// to keep in plain VGPRs -> MFMA reads A directly, no v_accvgpr copies.
// Single depth-4 acc chain per tile (2 accs total) minimizes acc init/readback.
// Numerics = r14 (fresh 16/S_t scale, 2 barriers/step): absmax 8.0 proven.
__global__ __launch_bounds__(1024, 1) void k_scan(
        const int* __restrict__ obs, const float* __restrict__ lp2,
        const float* __restrict__ Mrow, const u32* __restrict__ PAu,
        const float* __restrict__ EX, float* __restrict__ out) {
    int b = blockIdx.x, tid = threadIdx.x;
    int w = tid >> 6, l = tid & 63;
    int h32 = (l >> 4) * 32;              // byte offset of this lane's B slice
    int r4 = (l >> 4) * 4;                // row group within a 16-row tile
    __shared__ unsigned char us8[NN] __attribute__((aligned(64)));
    __shared__ float rB[16] __attribute__((aligned(16)));
    __shared__ int obs_s[MM];
    if (tid < MM) obs_s[tid] = obs[b * MM + tid];

    // C_M (8 loads + wave reduce)
    float mm = -INFINITY;
#pragma unroll
    for (int q = 0; q < 8; ++q) mm = fmaxf(mm, Mrow[q * 64 + l]);
    float C_M = wave_max(mm);

    // --- stage A-fragments: 8 x i32x8 per lane (2 tiles x 4 k-chunks) ---
    // No pin: 64 regs fits the (1024,1) budget; compiler keeps them resident.
    i32x8 pa[8];
#pragma unroll
    for (int ti = 0; ti < 2; ++ti)
#pragma unroll
        for (int kc = 0; kc < 4; ++kc)
            pa[ti * 4 + kc] = *(const i32x8*)(PAu
                + ((size_t)(((w * 2 + ti) * 4 + kc) * 64) + l) * 8);

    int ub0 = (w * 2 + 0) * 16 + r4;      // publish byte addresses
    int ub1 = (w * 2 + 1) * 16 + r4;
    __syncthreads();                      // obs_s ready

    // ---- t = 0: e = EX[o0] * lp2 ----
    int o0 = __builtin_amdgcn_readfirstlane(obs_s[0]);
    f32x4 e0, e1;
    float loc = 0.f;
    {
        const float* exr = EX + (size_t)o0 * NN;
        f32x4 xa = *(const f32x4*)(exr + (w * 2 + 0) * 16 + r4);
        f32x4 xb = *(const f32x4*)(exr + (w * 2 + 1) * 16 + r4);
        f32x4 pa0 = *(const f32x4*)(lp2 + (w * 2 + 0) * 16 + r4);
        f32x4 pb0 = *(const f32x4*)(lp2 + (w * 2 + 1) * 16 + r4);
        e0 = xa * pa0; e1 = xb * pb0;
#pragma unroll
        for (int r = 0; r < 4; ++r) loc += e0[r] + e1[r];
    }
    loc += __shfl_xor(loc, 16);
    loc += __shfl_xor(loc, 32);
    if (l == 0) rB[w] = loc;
    __syncthreads();                      // B1
    f32x4 sv0 = *(const f32x4*)rB;
    f32x4 sv1 = *(const f32x4*)(rB + 4);
    f32x4 sv2 = *(const f32x4*)(rB + 8);
    f32x4 sv3 = *(const f32x4*)(rB + 12);
    f32x4 svs = (sv0 + sv1) + (sv2 + sv3);
    float S = (svs[0] + svs[1]) + (svs[2] + svs[3]);
    S = fmaxf(S, 1e-35f);
    float sc = __builtin_amdgcn_rcpf(S) * 16.f;
    if ((l & 15) == 0) {
        int d0 = 0, d1 = 0;
        d0 = __builtin_amdgcn_cvt_pk_fp8_f32(e0[0] * sc, e0[1] * sc, d0, false);
        d0 = __builtin_amdgcn_cvt_pk_fp8_f32(e0[2] * sc, e0[3] * sc, d0, true);
        d1 = __builtin_amdgcn_cvt_pk_fp8_f32(e1[0] * sc, e1[1] * sc, d1, false);
        d1 = __builtin_amdgcn_cvt_pk_fp8_f32(e1[2] * sc, e1[3] * sc, d1, true);
        *(u32*)&us8[ub0] = (u32)d0;
        *(u32*)&us8[ub1] = (u32)d1;
    }
    __syncthreads();                      // B2: us8 ready
    float lS = __logf(S);
    if (tid == 0) out[(size_t)b * MM + 0] = lS;
    float K = C_M + lS;                   // Omega_1

    // prefetch t=1 emission row
    f32x4 xn0, xn1;
    {
        int on = __builtin_amdgcn_readfirstlane(obs_s[1]);
        const float* exr = EX + (size_t)on * NN;
        xn0 = *(const f32x4*)(exr + (w * 2 + 0) * 16 + r4);
        xn1 = *(const f32x4*)(exr + (w * 2 + 1) * 16 + r4);
    }

    // ---- main scan t >= 1 ----
#pragma unroll 1
    for (int t = 1; t < MM; ++t) {
        const unsigned char* ub = us8;
        f32x4 s0 = {0.f,0.f,0.f,0.f}, s1 = {0.f,0.f,0.f,0.f};
        __builtin_amdgcn_s_setprio(1);
#pragma unroll
        for (int kc = 0; kc < 4; ++kc) {   // 2 chains of depth 4, 8 MFMA total
            i32x8 bb = *(const i32x8*)(ub + kc * 128 + h32);
            s0 = __builtin_amdgcn_mfma_scale_f32_16x16x128_f8f6f4(
                     pa[0 * 4 + kc], bb, s0, 0, 0, 0, SCL1, 0, SCL1);
            s1 = __builtin_amdgcn_mfma_scale_f32_16x16x128_f8f6f4(
                     pa[1 * 4 + kc], bb, s1, 0, 0, 0, SCL1, 0, SCL1);
        }
        __builtin_amdgcn_s_setprio(0);

        // e = ex * s_raw (ex prefetched last step)
        e0 = xn0 * s0; e1 = xn1 * s1;
        loc = 0.f;
#pragma unroll
        for (int r = 0; r < 4; ++r) loc += e0[r] + e1[r];

        // prefetch t+1 emission row (in flight across barriers — r14-proven)
        {
            int on = __builtin_amdgcn_readfirstlane(
                         obs_s[(t + 1 < MM) ? t + 1 : t]);
            const float* exr = EX + (size_t)on * NN;
            xn0 = *(const f32x4*)(exr + (w * 2 + 0) * 16 + r4);
            xn1 = *(const f32x4*)(exr + (w * 2 + 1) * 16 + r4);
        }

        loc += __shfl_xor(loc, 16);
        loc += __shfl_xor(loc, 32);
        if (l == 0) rB[w] = loc;
        __syncthreads();                  // B1: rB ready (us8 reads done too)
        sv0 = *(const f32x4*)rB;
        sv1 = *(const f32x4*)(rB + 4);
        sv2 = *(const f32x4*)(rB + 8);
        sv3 = *(const f32x4*)(rB + 12);
        svs = (sv0 + sv1) + (sv2 + sv3);
        S = (svs[0] + svs[1]) + (svs[2] + svs[3]);
        S = fmaxf(S, 1e-35f);
        sc = __builtin_amdgcn_rcpf(S) * 16.f;
        if ((l & 15) == 0) {
            int d0 = 0, d1 = 0;
            d0 = __builtin_amdgcn_cvt_pk_fp8_f32(e0[0] * sc, e0[1] * sc, d0, false);
            d0 = __builtin_amdgcn_cvt_pk_fp8_f32(e0[2] * sc, e0[3] * sc, d0, true);
            d1 = __builtin_amdgcn_cvt_pk_fp8_f32(e1[0] * sc, e1[1] * sc, d1, false);
            d1 = __builtin_amdgcn_cvt_pk_fp8_f32(e1[2] * sc, e1[3] * sc, d1, true);
            *(u32*)&us8[ub0] = (u32)d0;
            *(u32*)&us8[ub1] = (u32)d1;
        }
        __syncthreads();                  // B2: us8 ready for next step
        // deferred bookkeeping (overlaps next step's MFMA)
        float lSn = __logf(S);
        if (tid == 0) out[(size_t)b * MM + t] = K + lSn;
        K += C_M + lSn;                   // Omega_{t+1}
    }
}

extern "C" void kernel_launch(void* const* d_in, const int* in_sizes, int n_in,
                              void* d_out, int out_size, void* d_ws, size_t ws_size,
                              hipStream_t stream) {
    const int*   obs = (const int*)d_in[0];
    const float* pri = (const float*)d_in[1];
    const float* T   = (const float*)d_in[2];
    const float* E   = (const float*)d_in[3];
    float* out = (float*)d_out;
    char* ws = (char*)d_ws;

    float* c   = (float*)(ws + 0);
    float* lp2 = (float*)(ws + 2048);
    float* M   = (float*)(ws + 4096);
    u32*   PA  = (u32*)(ws + 8192);                       // 256 KB fp8 A-frags
    float* EX  = (float*)(ws + 8192 + 256 * 1024);        // 512 KB

    k_col_lse<<<512, 64, 0, stream>>>(T, c);
    k_rowM   <<<512, 64, 0, stream>>>(T, c, M);
    k_prep   <<<641, 64, 0, stream>>>(T, c, M, pri, E, lp2, PA, EX);
    k_scan   <<<BB, 1024, 0, stream>>>(obs, lp2, M, PA, EX, out);
}